// Round 12
// baseline (195.527 us; speedup 1.0000x reference)
//
#include <hip/hip_runtime.h>
#include <math.h>

// ---------------------------------------------------------------------------
// GATv2 encoder. r11 evidence: aggregate is VALU+latency bound (FETCH 80MB vs
// 12.8MB replays -> same 44.5us; VALUBusy 70%). This round:
// (1) aggregate 2-deep pipelined edge-quads (next quad's gathers in flight
//     during current quad's compute);
// (2) CSR build 9 -> 4 kernels (inline LDS base-scan; fused count+scan+fill);
// (3) GEMM 128 rows/block (2 row-tiles/wave, shared B frag).
// ---------------------------------------------------------------------------

#define D 128
#define H 8
#define C 16
#define NBIN 256

typedef __attribute__((ext_vector_type(8))) short bf16x8v;
typedef __attribute__((ext_vector_type(4))) float f32x4v;

static __device__ __forceinline__ float bf2f(unsigned int u16) {
    union { unsigned int i; float f; } x; x.i = u16 << 16; return x.f;
}
static __device__ __forceinline__ unsigned short f2bf(float f) {
    union { float f; unsigned int i; } x; x.f = f;
    unsigned int r = x.i + 0x7fffu + ((x.i >> 16) & 1u);   // RNE
    return (unsigned short)(r >> 16);
}
static __device__ __forceinline__ float gelu_f(float v) {
    return 0.5f * v * (1.0f + erff(v * 0.70710678118654752f));
}
static __device__ __forceinline__ float exp2_hw(float x) {   // v_exp_f32 = 2^x
    float r;
    asm("v_exp_f32 %0, %1" : "=v"(r) : "v"(x));
    return r;
}
#define DPP_ADD(v, ctrl) \
    (v) += __builtin_bit_cast(float, __builtin_amdgcn_update_dpp( \
        0, __builtin_bit_cast(int, (v)), (ctrl), 0xf, 0xf, true))

// ---------------- W transpose+cast (parallel, LDS-tiled) --------------------
__global__ __launch_bounds__(256) void transpose_w2(
    const float* __restrict__ W, const float* __restrict__ outW,
    unsigned short* __restrict__ wbf)
{
    __shared__ unsigned short tile[128][17];
    int blk = blockIdx.x, t = threadIdx.x;
    int mat = blk >> 3, s = blk & 7;
    const float* src = (mat < 2) ? (W + (size_t)mat * D * D) : outW;
    unsigned short* dst = wbf + (size_t)mat * D * D;
    int n0 = s * 16;
#pragma unroll
    for (int it = 0; it < 8; ++it) {
        int idx = it * 256 + t;
        int k = idx >> 4, n = idx & 15;
        tile[k][n] = f2bf(src[k * D + n0 + n]);
    }
    __syncthreads();
#pragma unroll
    for (int it = 0; it < 8; ++it) {
        int idx = it * 256 + t;
        int n = idx >> 7, k = idx & 127;
        dst[(size_t)(n0 + n) * D + k] = tile[k][n];
    }
}

// ----------------------------- MFMA GEMM (128 rows/block) ------------------
template<int IN_BF, int OUT_BF, int GELU>
__global__ __launch_bounds__(256) void gemm_mfma(
    const void* __restrict__ Xv, const unsigned short* __restrict__ Wt,
    const float* __restrict__ bias, void* __restrict__ Outv, int nrows)
{
    __shared__ short Wlds[128 * 128];   // 32 KB

    const int t  = threadIdx.x;
    const int m0 = blockIdx.x * 128;

#pragma unroll
    for (int w = 0; w < 8; ++w) {
        int cell = w * 256 + t;
        int col = cell >> 4, kg = cell & 15;
        uint4 q = reinterpret_cast<const uint4*>(Wt)[col * 16 + kg];
        *reinterpret_cast<uint4*>(&Wlds[(col * 16 + (kg ^ (col & 7))) * 8]) = q;
    }

    const int l  = t & 63;
    const int wv = t >> 6;
    const int g  = l >> 4;
    const int r  = l & 15;

    bf16x8v afrag[2][4];
#pragma unroll
    for (int rt = 0; rt < 2; ++rt) {
        const int row = m0 + (rt * 4 + wv) * 16 + r;
        const bool rv = row < nrows;
#pragma unroll
        for (int kk = 0; kk < 4; ++kk) {
            int kg = kk * 4 + g;
            float v[8];
            if (IN_BF) {
                uint4 q = make_uint4(0, 0, 0, 0);
                if (rv) q = reinterpret_cast<const uint4*>(Xv)[(size_t)row * 16 + kg];
                if (GELU) {
                    unsigned int qq[4] = {q.x, q.y, q.z, q.w};
#pragma unroll
                    for (int j = 0; j < 4; ++j) {
                        v[2 * j]     = gelu_f(bf2f(qq[j] & 0xffffu));
                        v[2 * j + 1] = gelu_f(bf2f(qq[j] >> 16));
                    }
                    short pk[8];
#pragma unroll
                    for (int j = 0; j < 8; ++j) pk[j] = (short)f2bf(v[j]);
                    afrag[rt][kk] = *reinterpret_cast<bf16x8v*>(pk);
                } else {
                    afrag[rt][kk] = __builtin_bit_cast(bf16x8v, q);
                }
            } else {
                float4 a = make_float4(0.f, 0.f, 0.f, 0.f), b = a;
                if (rv) {
                    a = reinterpret_cast<const float4*>(Xv)[(size_t)row * 32 + kg * 2];
                    b = reinterpret_cast<const float4*>(Xv)[(size_t)row * 32 + kg * 2 + 1];
                }
                v[0] = a.x; v[1] = a.y; v[2] = a.z; v[3] = a.w;
                v[4] = b.x; v[5] = b.y; v[6] = b.z; v[7] = b.w;
                if (GELU) {
#pragma unroll
                    for (int j = 0; j < 8; ++j) v[j] = gelu_f(v[j]);
                }
                short pk[8];
#pragma unroll
                for (int j = 0; j < 8; ++j) pk[j] = (short)f2bf(v[j]);
                afrag[rt][kk] = *reinterpret_cast<bf16x8v*>(pk);
            }
        }
    }
    __syncthreads();

    f32x4v acc[2][8];
#pragma unroll
    for (int rt = 0; rt < 2; ++rt)
#pragma unroll
        for (int ct = 0; ct < 8; ++ct) acc[rt][ct] = (f32x4v){0.f, 0.f, 0.f, 0.f};

#pragma unroll
    for (int kk = 0; kk < 4; ++kk) {
        int kg = kk * 4 + g;
#pragma unroll
        for (int ct = 0; ct < 8; ++ct) {
            int col = ct * 16 + r;
            bf16x8v b = *reinterpret_cast<const bf16x8v*>(
                &Wlds[(col * 16 + (kg ^ (col & 7))) * 8]);
            acc[0][ct] = __builtin_amdgcn_mfma_f32_16x16x32_bf16(afrag[0][kk], b, acc[0][ct], 0, 0, 0);
            acc[1][ct] = __builtin_amdgcn_mfma_f32_16x16x32_bf16(afrag[1][kk], b, acc[1][ct], 0, 0, 0);
        }
    }

#pragma unroll
    for (int rt = 0; rt < 2; ++rt)
#pragma unroll
    for (int ct = 0; ct < 8; ++ct) {
        int col = ct * 16 + r;
        float bj = bias ? bias[col] : 0.f;
#pragma unroll
        for (int i = 0; i < 4; ++i) {
            int rr = m0 + (rt * 4 + wv) * 16 + g * 4 + i;
            if (rr < nrows) {
                float val = acc[rt][ct][i] + bj;
                if (OUT_BF)
                    reinterpret_cast<unsigned short*>(Outv)[(size_t)rr * 128 + col] = f2bf(val);
                else
                    reinterpret_cast<float*>(Outv)[(size_t)rr * 128 + col] = val;
            }
        }
    }
}

// ------------------- CSR build: LDS-bucketed, 4 kernels --------------------
__global__ __launch_bounds__(256) void hist_pass(
    const int* __restrict__ dst, int* __restrict__ bh, int E, int chunk, int nblk)
{
    __shared__ int h[NBIN];
    int t = threadIdx.x, b = blockIdx.x;
    h[t] = 0;
    __syncthreads();
    int lo = b * chunk, hi = min(E, lo + chunk);
    for (int i = lo + t; i < hi; i += 256) atomicAdd(&h[dst[i] >> 8], 1);
    __syncthreads();
    bh[t * nblk + b] = h[t];
}

// per-bin exclusive scan over blocks (in place); tot[bin] = bin total
__global__ __launch_bounds__(256) void bin_scan(
    int* __restrict__ bh, int* __restrict__ tot, int nblk)
{
    __shared__ int sh[256];
    int bin = blockIdx.x, t = threadIdx.x;
    int v = (t < nblk) ? bh[bin * nblk + t] : 0;
    sh[t] = v;
    __syncthreads();
#pragma unroll
    for (int off = 1; off < 256; off <<= 1) {
        int x = (t >= off) ? sh[t - off] : 0;
        __syncthreads();
        sh[t] += x;
        __syncthreads();
    }
    if (t < nblk) bh[bin * nblk + t] = sh[t] - v;
    if (t == 255) tot[bin] = sh[255];
}

// scatter into bucket-contiguous bout; bases re-derived in LDS (scan of tot)
__global__ __launch_bounds__(256) void scatter_bucket2(
    const int* __restrict__ dst, const int* __restrict__ src,
    const int* __restrict__ bh, const int* __restrict__ tot,
    int2* __restrict__ bout, int E, int chunk, int nblk)
{
    __shared__ int sh[NBIN];
    __shared__ int cur[NBIN];
    int t = threadIdx.x, b = blockIdx.x;
    int tv = tot[t];
    sh[t] = tv;
    __syncthreads();
#pragma unroll
    for (int off = 1; off < 256; off <<= 1) {
        int x = (t >= off) ? sh[t - off] : 0;
        __syncthreads();
        sh[t] += x;
        __syncthreads();
    }
    cur[t] = (sh[t] - tv) + bh[t * nblk + b];
    __syncthreads();
    int lo = b * chunk, hi = min(E, lo + chunk);
    for (int i = lo + t; i < hi; i += 256) {
        int d = dst[i];
        int p = atomicAdd(&cur[d >> 8], 1);
        bout[p] = make_int2(src[i], d);
    }
}

// fused per-bucket: count (LDS) -> LDS scan -> rowptr write -> rank+fill
__global__ __launch_bounds__(256) void fill_fused(
    const int2* __restrict__ bout, const int* __restrict__ tot,
    int* __restrict__ rowptr, int* __restrict__ slist, int N, int E)
{
    __shared__ int sh[NBIN];
    __shared__ int cnt[NBIN];
    __shared__ int cur[NBIN];
    int b = blockIdx.x, t = threadIdx.x;

    // bucket range from inclusive scan of tot
    int tv = tot[t];
    sh[t] = tv;
    __syncthreads();
#pragma unroll
    for (int off = 1; off < 256; off <<= 1) {
        int x = (t >= off) ? sh[t - off] : 0;
        __syncthreads();
        sh[t] += x;
        __syncthreads();
    }
    int hi = sh[b];
    int lo = hi - tot[b];

    // per-dst count within bucket
    cnt[t] = 0;
    __syncthreads();
    for (int i = lo + t; i < hi; i += 256) atomicAdd(&cnt[bout[i].y & 255], 1);
    __syncthreads();

    // LDS scan of counts -> per-dst start
    int cv = cnt[t];
    sh[t] = cv;
    __syncthreads();
#pragma unroll
    for (int off = 1; off < 256; off <<= 1) {
        int x = (t >= off) ? sh[t - off] : 0;
        __syncthreads();
        sh[t] += x;
        __syncthreads();
    }
    int start = lo + sh[t] - cv;
    int d0 = b * 256 + t;
    if (d0 < N) rowptr[d0] = start;
    if (b == (int)gridDim.x - 1 && t == 255) rowptr[N] = E;
    cur[t] = start;
    __syncthreads();

    // rank + fill (writes land in small L2-resident window)
    for (int i = lo + t; i < hi; i += 256) {
        int2 e = bout[i];
        int p = atomicAdd(&cur[e.y & 255], 1);
        slist[p] = e.x;
    }
}

// ----------- fused logits + softmax + aggregate (pipelined quads) ----------
// wave per dst node; lane = channels (2*lane,2*lane+1); head = lane>>3.
#define PROC(u, k) \
    float h##k##x = bf2f((u) & 0xffffu), h##k##y = bf2f((u) >> 16); \
    float a##k = h##k##x + hdx; a##k = fmaxf(a##k, 0.2f * a##k); \
    float b##k = h##k##y + hdy; b##k = fmaxf(b##k, 0.2f * b##k); \
    float p##k = a##k * aw.x + b##k * aw.y; \
    DPP_ADD(p##k, 0xB1); DPP_ADD(p##k, 0x4E); DPP_ADD(p##k, 0x141); \
    float e##k = exp2_hw(p##k);

#define QUAD_BODY(U0, U1, U2, U3) \
    { PROC(U0, 0) PROC(U1, 1) PROC(U2, 2) PROC(U3, 3) \
      ssum += (e0 + e1) + (e2 + e3); \
      accx = fmaf(e0, h0x, fmaf(e1, h1x, fmaf(e2, h2x, fmaf(e3, h3x, accx)))); \
      accy = fmaf(e0, h0y, fmaf(e1, h1y, fmaf(e2, h2y, fmaf(e3, h3y, accy)))); }

__global__ __launch_bounds__(256) void aggregate(
    const unsigned int* __restrict__ Hm,
    const int* __restrict__ rowptr, const int* __restrict__ slist,
    const float* __restrict__ att, const float* __restrict__ bias,
    unsigned int* __restrict__ Outv, int n)
{
    int wid  = threadIdx.x >> 6;
    int lane = threadIdx.x & 63;
    int d = blockIdx.x * 4 + wid;
    if (d >= n) return;

    int beg = rowptr[d];
    int end = rowptr[d + 1];

    unsigned int ud = Hm[((unsigned)d << 6) | lane];
    float hdx = bf2f(ud & 0xffffu), hdy = bf2f(ud >> 16);
    float2 aw = reinterpret_cast<const float2*>(att)[lane];
    aw.x *= 1.44269504088896f;    // fold log2(e): exp(p) = 2^(p*log2e)
    aw.y *= 1.44269504088896f;

    float ssum = 0.f, accx = 0.f, accy = 0.f;

    int nfull = (end - beg) >> 2;   // edge quads
    int ii = beg;
    unsigned cu0, cu1, cu2, cu3;
    if (nfull) {
        cu0 = Hm[((unsigned)slist[ii]     << 6) | lane];
        cu1 = Hm[((unsigned)slist[ii + 1] << 6) | lane];
        cu2 = Hm[((unsigned)slist[ii + 2] << 6) | lane];
        cu3 = Hm[((unsigned)slist[ii + 3] << 6) | lane];
    }
    for (int q = 1; q < nfull; ++q) {
        int j = ii + 4;
        unsigned nu0 = Hm[((unsigned)slist[j]     << 6) | lane];
        unsigned nu1 = Hm[((unsigned)slist[j + 1] << 6) | lane];
        unsigned nu2 = Hm[((unsigned)slist[j + 2] << 6) | lane];
        unsigned nu3 = Hm[((unsigned)slist[j + 3] << 6) | lane];
        QUAD_BODY(cu0, cu1, cu2, cu3)
        cu0 = nu0; cu1 = nu1; cu2 = nu2; cu3 = nu3;
        ii = j;
    }
    if (nfull) {
        QUAD_BODY(cu0, cu1, cu2, cu3)
        ii += 4;
    }
    for (; ii < end; ++ii) {
        unsigned u0 = Hm[((unsigned)slist[ii] << 6) | lane];
        PROC(u0, 9)
        ssum += e9;
        accx = fmaf(e9, h9x, accx);
        accy = fmaf(e9, h9y, accy);
    }

    float inv = 1.f / (ssum + 1e-16f);
    float2 bv = reinterpret_cast<const float2*>(bias)[lane];
    float ox = accx * inv + bv.x;
    float oy = accy * inv + bv.y;
    Outv[((unsigned)d << 6) | lane] =
        (unsigned int)f2bf(ox) | ((unsigned int)f2bf(oy) << 16);
}

// ------------------------------ LayerNorm ----------------------------------
__global__ __launch_bounds__(256) void ln_kernel(
    const float* __restrict__ Y, const float* __restrict__ g,
    const float* __restrict__ b, float* __restrict__ Out, int n)
{
    int wid  = threadIdx.x >> 6;
    int lane = threadIdx.x & 63;
    int r = blockIdx.x * 4 + wid;
    if (r >= n) return;

    float2 v = reinterpret_cast<const float2*>(Y)[(size_t)r * 64 + lane];
    float sum = v.x + v.y;
#pragma unroll
    for (int off = 32; off >= 1; off >>= 1) sum += __shfl_xor(sum, off);
    float mu = sum * (1.f / 128.f);
    float dx = v.x - mu, dy = v.y - mu;
    float sq = dx * dx + dy * dy;
#pragma unroll
    for (int off = 32; off >= 1; off >>= 1) sq += __shfl_xor(sq, off);
    float inv = rsqrtf(sq * (1.f / 128.f) + 1e-12f);
    float2 gv = reinterpret_cast<const float2*>(g)[lane];
    float2 bv = reinterpret_cast<const float2*>(b)[lane];
    float2 o;
    o.x = dx * inv * gv.x + bv.x;
    o.y = dy * inv * gv.y + bv.y;
    reinterpret_cast<float2*>(Out)[(size_t)r * 64 + lane] = o;
}

// ---------------------------------------------------------------------------
extern "C" void kernel_launch(void* const* d_in, const int* in_sizes, int n_in,
                              void* d_out, int out_size, void* d_ws, size_t ws_size,
                              hipStream_t stream)
{
    const float* x    = (const float*)d_in[0];
    const int*   edge = (const int*)d_in[1];     // int32 (harness converts int64)
    const float* W    = (const float*)d_in[2];
    const float* att  = (const float*)d_in[3];
    const float* bias = (const float*)d_in[4];
    const float* outW = (const float*)d_in[5];
    const float* outb = (const float*)d_in[6];
    const float* lng  = (const float*)d_in[7];
    const float* lnb  = (const float*)d_in[8];

    const int N  = in_sizes[0] / D;
    const int E  = in_sizes[1] / 2;
    const int NT = out_size / D;

    const int* srcp = edge;
    const int* dstp = edge + E;

    auto align256 = [](size_t v) { return (v + 255) & ~(size_t)255; };
    auto cdiv = [](int a, int b) { return (a + b - 1) / b; };

    const int CHUNK = cdiv(E, 256);
    const int NBLK  = cdiv(E, CHUNK);        // <= 256
    const int NBKT  = cdiv(N, 256);

    size_t ybytes = (size_t)NT * D * 4;
    size_t hb     = (size_t)N * D * 2;
    size_t hbytes = align256(hb > ybytes ? hb : ybytes);

    char* wp = (char*)d_ws;
    size_t off = 0;
    void* hbuf   = (void*)(wp + off); off += hbytes;
    unsigned short* wbf = (unsigned short*)(wp + off); off += align256((size_t)3 * D * D * 2);
    int*  rowptr = (int*)(wp + off);  off += align256((size_t)(N + 1) * 4);
    int*  slist  = (int*)(wp + off);  off += align256((size_t)E * 4);
    int2* bout   = (int2*)(wp + off); off += align256((size_t)E * 8);
    int*  bh     = (int*)(wp + off);  off += align256((size_t)NBIN * NBLK * 4);
    int*  tot    = (int*)(wp + off);  off += align256((size_t)NBIN * 4);
    unsigned int* xb = (unsigned int*)d_out;   // bf16 activations in d_out
    float* ybuf = (float*)hbuf;                // head GEMM out reuses h buffer
    (void)n_in; (void)ws_size;

    // ---- weight transpose+cast ----
    transpose_w2<<<24, 256, 0, stream>>>(W, outW, wbf);

    // ---- CSR build (4 kernels) ----
    hist_pass<<<NBLK, 256, 0, stream>>>(dstp, bh, E, CHUNK, NBLK);
    bin_scan<<<NBIN, 256, 0, stream>>>(bh, tot, NBLK);
    scatter_bucket2<<<NBLK, 256, 0, stream>>>(dstp, srcp, bh, tot, bout, E, CHUNK, NBLK);
    fill_fused<<<NBKT, 256, 0, stream>>>(bout, tot, rowptr, slist, N, E);

    // ---- layer 0: h = x @ W0 (f32 in, bf16 out) ----
    gemm_mfma<0,1,0><<<cdiv(N, 128), 256, 0, stream>>>(x, wbf, nullptr, hbuf, N);
    aggregate<<<cdiv(N, 4), 256, 0, stream>>>((unsigned int*)hbuf, rowptr, slist,
                                              att, bias, xb, N);
    // ---- layer 1: h = gelu(x) @ W1 (bf16 in, bf16 out) ----
    gemm_mfma<1,1,1><<<cdiv(N, 128), 256, 0, stream>>>(xb, wbf + D * D, nullptr, hbuf, N);
    aggregate<<<cdiv(N, 4), 256, 0, stream>>>((unsigned int*)hbuf, rowptr, slist,
                                              att + H * C, bias + D, xb, N);
    // ---- head: y = x @ outW + outb (bf16 in, f32 out), then LN ----
    gemm_mfma<1,0,0><<<cdiv(NT, 128), 256, 0, stream>>>(xb, wbf + 2 * D * D, outb, ybuf, NT);
    ln_kernel<<<cdiv(NT, 4), 256, 0, stream>>>(ybuf, lng, lnb, (float*)d_out, NT);
}